// Round 2
// baseline (481.433 us; speedup 1.0000x reference)
//
#include <hip/hip_runtime.h>

// WindowAttention MFMA v4: B=32, 56x56, C=192, heads=6, d=32, ws=7, NW=49
//  ln:   prep (weights->bf16, bias table) folded in + LayerNorm pass -> xng
//        (window-partitioned, zero-padded rows 49..63, bf16) in d_out scratch.
//  k1:   per (window, 3-head half): MFMA QKV -> MFMA attention.
//        v4: QKV phase preloads ALL 42 global fragments into registers
//        (24 A from xng + 18 B from wq, kt-interleaved) + sched_barrier fence
//        -> 42-deep MLP per wave instead of 7-deep per kt (VGPR 48 -> ~230).
//  k2:   proj GEMM direct-global MFMA. v4: preload all 36 fragments (same fix).

typedef __bf16 bf16x8 __attribute__((ext_vector_type(8)));
typedef float  f32x4  __attribute__((ext_vector_type(4)));
union U128 { uint4 u; bf16x8 v; };

__device__ __forceinline__ f32x4 mfma16(bf16x8 a, bf16x8 b, f32x4 c){
  return __builtin_amdgcn_mfma_f32_16x16x32_bf16(a, b, c, 0, 0, 0);
}
__device__ __forceinline__ f32x4 f4zero(){
  f32x4 z; z[0]=0.f; z[1]=0.f; z[2]=0.f; z[3]=0.f; return z;
}
__device__ __forceinline__ unsigned short f2bf(float f){
  union{float f; unsigned int i;} x; x.f = f;
  unsigned int r = x.i + 0x7fffu + ((x.i >> 16) & 1u);  // RNE
  return (unsigned short)(r >> 16);
}
__device__ __forceinline__ bf16x8 ldfrag(const unsigned short* p){
  U128 x; x.u = *(const uint4*)p; return x.v;
}
__device__ __forceinline__ int div7(int t){ return (t * 9363) >> 16; }  // exact for t<64

// ---------------- ln: prep (folded) + LayerNorm + window partition -> xng ----------------
// grid 32768 x 256 (4 waves/block, 1 row/wave). xng[wi*64 + t][192], rows 49..63 zeroed.
// Blocks 0..431 additionally convert weights to bf16 and expand the bias table.
__global__ __launch_bounds__(256, 8) void wa_ln(
    const float* __restrict__ x, const float* __restrict__ gamma,
    unsigned short* __restrict__ xng,
    const float* __restrict__ qkv_w, const float* __restrict__ proj_w,
    const float* __restrict__ rpb,
    unsigned short* __restrict__ wq, unsigned short* __restrict__ wp,
    float* __restrict__ bt)
{
  const int tid  = threadIdx.x;

  // --- folded prep (first 432 blocks) ---
  if (blockIdx.x < 432){
    int i = blockIdx.x * 256 + tid;
    if (i < 576*192) wq[i] = f2bf(qkv_w[i]);
    if (i < 192*192) wp[i] = f2bf(proj_w[i]);
    if (i < 6*64*64){
      // btT layout: [head][t][l16][nt] so one lane reads its 4 bias values as a dwordx4
      int head = i >> 12, t = (i >> 6) & 63, j = i & 63;
      int l16 = j >> 2, nt = j & 3;
      int col = nt*16 + l16;
      float v;
      if (t < 49 && col < 49){
        int tr = div7(t),   tc = t   - tr*7;
        int jr = div7(col), jc = col - jr*7;
        v = rpb[((tr - jr + 6)*13 + (tc - jc + 6))*6 + head];
      } else {
        v = (col >= 49) ? -3.0e38f : 0.0f;  // mask folded into bias
      }
      bt[i] = v;
    }
  }

  // --- LayerNorm ---
  const int wave = tid >> 6, lane = tid & 63;
  const int wid  = blockIdx.x * 4 + wave;        // wi*64 + t
  const int wi   = wid >> 6, t = wid & 63;
  unsigned short* dst = xng + (size_t)wid * 192;
  if (t >= 49){
    if (lane < 24){ const uint4 z = {0u,0u,0u,0u}; *(uint4*)&dst[lane*8] = z; }
    return;
  }
  const int b = wi >> 6, wr = (wi >> 3) & 7, wc = wi & 7;
  const int tr = div7(t), tc = t - tr*7;
  const float* xt = x + ((size_t)b*3136 + (size_t)((wr*7 + tr)*56 + wc*7 + tc)) * 192;
  float v0 = xt[lane], v1 = xt[lane+64], v2 = xt[lane+128];
  float s  = v0 + v1 + v2;
  float sq = v0*v0 + v1*v1 + v2*v2;
#pragma unroll
  for (int off = 32; off > 0; off >>= 1){
    s  += __shfl_xor(s,  off);
    sq += __shfl_xor(sq, off);
  }
  float mu  = s * (1.0f/192.0f);
  float var = sq * (1.0f/192.0f) - mu*mu;
  float inv = rsqrtf(var + 1e-5f);
  dst[lane]      = f2bf((v0 - mu)*inv*gamma[lane]);
  dst[lane+64]   = f2bf((v1 - mu)*inv*gamma[lane+64]);
  dst[lane+128]  = f2bf((v2 - mu)*inv*gamma[lane+128]);
}

// ---------------- k1: QKV + attention (MFMA), LDS = 44.5 KB -> 3 blocks/CU ----------------
// grid 4096 = 2048 windows x 2 half (3 heads each); block 384 (6 waves)
#define QKS 40
__global__ __launch_bounds__(384, 4) void wa_k1(
    const unsigned short* __restrict__ xng, const float* __restrict__ bt,
    const unsigned short* __restrict__ wq, const float* __restrict__ qkv_b,
    unsigned short* __restrict__ attn)
{
  __shared__ __align__(16) unsigned short qk[6*64*QKS];   // qs | ks ; P overlays after barrier 2
  __shared__ __align__(16) unsigned short vt[3*32*72];    // V^T [hl][d][t], stride 72

  const int blk  = blockIdx.x;
  const int wi   = blk >> 1;
  const int h0   = (blk & 1) * 3;
  const int b    = wi >> 6;
  const int wr   = (wi >> 3) & 7;
  const int wc   = wi & 7;
  const int tid  = threadIdx.x;
  const int wave = tid >> 6;
  const int lane = tid & 63;
  const int quad = lane >> 4;
  const int l16  = lane & 15;

  unsigned short* const qs = qk;               // Q (scaled) [hl][t][d], stride 40
  unsigned short* const ks = qk + 3*64*QKS;    // K          [hl][t][d], stride 40

  // ---- QKV GEMM: wave w: section sec=w>>1 (q/k/v), 48 cols ----
  // v4: preload ALL fragments (42 loads in flight), then MFMA burst.
  {
    const int sec = wave >> 1;
    const int n0  = sec*192 + h0*32 + (wave & 1)*48;
    const unsigned short* xw = xng + (size_t)wi * 64 * 192;

    bf16x8 a[6][4], bwf[6][3];
#pragma unroll
    for (int kt = 0; kt < 6; kt++){
#pragma unroll
      for (int mt = 0; mt < 4; mt++)
        a[kt][mt] = ldfrag(&xw[(size_t)(mt*16 + l16)*192 + kt*32 + quad*8]);
#pragma unroll
      for (int nt = 0; nt < 3; nt++)
        bwf[kt][nt] = ldfrag(&wq[(size_t)(n0 + nt*16 + l16)*192 + kt*32 + quad*8]);
    }
    __builtin_amdgcn_sched_barrier(0);   // keep all 42 loads issued before the MFMA burst

    f32x4 acc[4][3];
#pragma unroll
    for (int mt = 0; mt < 4; mt++)
#pragma unroll
      for (int nt = 0; nt < 3; nt++) acc[mt][nt] = f4zero();

#pragma unroll
    for (int kt = 0; kt < 6; kt++)
#pragma unroll
      for (int mt = 0; mt < 4; mt++)
#pragma unroll
        for (int nt = 0; nt < 3; nt++)
          acc[mt][nt] = mfma16(a[kt][mt], bwf[kt][nt], acc[mt][nt]);

    const float scale = 0.17677669529663687f;  // 1/sqrt(32)
#pragma unroll
    for (int nt = 0; nt < 3; nt++){
      const int bc = (wave & 1)*48 + nt*16 + l16;  // 0..95 within section
      const int hl2 = bc >> 5, d = bc & 31;
      const float bias = qkv_b[n0 + nt*16 + l16];
#pragma unroll
      for (int mt = 0; mt < 4; mt++)
#pragma unroll
        for (int r = 0; r < 4; r++){
          const int row = mt*16 + quad*4 + r;
          const float val = acc[mt][nt][r] + bias;
          if (sec == 0)      qs[(hl2*64 + row)*QKS + d] = f2bf(val * scale);
          else if (sec == 1) ks[(hl2*64 + row)*QKS + d] = f2bf(val);
          else               vt[(hl2*32 + d)*72 + row]  = f2bf(val);
        }
    }
  }
  __syncthreads();

  // ---- Attention: wave -> (local head hl = w>>1, row-half = w&1) ----
  const int hl   = wave >> 1;
  const int half = wave & 1;
  const int head = h0 + hl;

  // bias prefetch (one dwordx4 per row) — issue first, hides under the QK ds_reads/MFMAs
  f32x4 bias4[2][4];
#pragma unroll
  for (int i = 0; i < 2; i++)
#pragma unroll
    for (int r = 0; r < 4; r++){
      const int t = half*32 + i*16 + quad*4 + r;
      bias4[i][r] = *(const f32x4*)&bt[head*4096 + t*64 + l16*4];
    }

  // QK^T (consumes qs/ks)
  bf16x8 aq[2];
#pragma unroll
  for (int i = 0; i < 2; i++)
    aq[i] = ldfrag(&qs[(hl*64 + half*32 + i*16 + l16)*QKS + quad*8]);

  f32x4 s[2][4];
#pragma unroll
  for (int nt = 0; nt < 4; nt++){
    bf16x8 bk = ldfrag(&ks[(hl*64 + nt*16 + l16)*QKS + quad*8]);
#pragma unroll
    for (int i = 0; i < 2; i++)
      s[i][nt] = mfma16(aq[i], bk, f4zero());
  }

  __syncthreads();   // qs/ks now dead everywhere -> safe to overlay P

  // ---- softmax rows; write P (stride 72) over qs/ks region; keep 1/l ----
  float linv[2][4];
#pragma unroll
  for (int i = 0; i < 2; i++)
#pragma unroll
    for (int r = 0; r < 4; r++){
      const f32x4 b4 = bias4[i][r];
#pragma unroll
      for (int nt = 0; nt < 4; nt++) s[i][nt][r] += b4[nt];
      float m = fmaxf(fmaxf(s[i][0][r], s[i][1][r]), fmaxf(s[i][2][r], s[i][3][r]));
#pragma unroll
      for (int off = 8; off > 0; off >>= 1) m = fmaxf(m, __shfl_xor(m, off));
      float l = 0.f;
      const int t = half*32 + i*16 + quad*4 + r;
#pragma unroll
      for (int nt = 0; nt < 4; nt++){
        float p = __expf(s[i][nt][r] - m);
        l += p;
        qk[hl*4608 + t*72 + nt*16 + l16] = f2bf(p);
      }
#pragma unroll
      for (int off = 8; off > 0; off >>= 1) l += __shfl_xor(l, off);
      linv[i][r] = 1.f / l;
    }

  // ---- PV: O(32x32 slice) = P rows[half*32..+32) x V(64x32) ----
  f32x4 o[2][2];
#pragma unroll
  for (int i = 0; i < 2; i++)
#pragma unroll
    for (int n2 = 0; n2 < 2; n2++) o[i][n2] = f4zero();
#pragma unroll
  for (int kt = 0; kt < 2; kt++){
    bf16x8 ap[2], bv[2];
#pragma unroll
    for (int i = 0; i < 2; i++)
      ap[i] = ldfrag(&qk[hl*4608 + (half*32 + i*16 + l16)*72 + kt*32 + quad*8]);
#pragma unroll
    for (int n2 = 0; n2 < 2; n2++)
      bv[n2] = ldfrag(&vt[(hl*32 + n2*16 + l16)*72 + kt*32 + quad*8]);
#pragma unroll
    for (int i = 0; i < 2; i++)
#pragma unroll
      for (int n2 = 0; n2 < 2; n2++)
        o[i][n2] = mfma16(ap[i], bv[n2], o[i][n2]);
  }

  // store O rows < 49, spatial order (window reverse), bf16
#pragma unroll
  for (int i = 0; i < 2; i++)
#pragma unroll
    for (int r = 0; r < 4; r++){
      const int t = half*32 + i*16 + quad*4 + r;
      if (t < 49){
        const int tr = div7(t), tcc = t - tr*7;
        const size_t base =
          ((size_t)b*3136 + (size_t)((wr*7 + tr)*56 + wc*7 + tcc))*192 + head*32;
        const float inv = linv[i][r];
        attn[base + l16]      = f2bf(o[i][0][r] * inv);
        attn[base + 16 + l16] = f2bf(o[i][1][r] * inv);
      }
    }
}

// ---------------- k2: proj GEMM direct-global (no LDS, no barrier) ----------------
// grid (784, 3); block 256 (4 waves); per block M=128, N=64; K=192.
// v4: preload all 36 fragments (kt-interleaved), then MFMA burst.
__global__ __launch_bounds__(256, 4) void wa_k2(
    const unsigned short* __restrict__ a, const unsigned short* __restrict__ wp,
    const float* __restrict__ pb, float* __restrict__ out)
{
  const int mblk = blockIdx.x;
  const int nblk = blockIdx.y;
  const int tid  = threadIdx.x;
  const int wave = tid >> 6;
  const int lane = tid & 63;
  const int quad = lane >> 4;
  const int l16  = lane & 15;

  bf16x8 av[6][2], bw[6][4];
#pragma unroll
  for (int kt = 0; kt < 6; kt++){
#pragma unroll
    for (int i = 0; i < 2; i++)
      av[kt][i] = ldfrag(&a[(size_t)(mblk*128 + (wave*2 + i)*16 + l16)*192 + kt*32 + quad*8]);
#pragma unroll
    for (int nt = 0; nt < 4; nt++)
      bw[kt][nt] = ldfrag(&wp[(size_t)(nblk*64 + nt*16 + l16)*192 + kt*32 + quad*8]);
  }
  __builtin_amdgcn_sched_barrier(0);   // keep all 36 loads issued before the MFMA burst

  f32x4 acc[2][4];
#pragma unroll
  for (int i = 0; i < 2; i++)
#pragma unroll
    for (int nt = 0; nt < 4; nt++) acc[i][nt] = f4zero();

#pragma unroll
  for (int kt = 0; kt < 6; kt++)
#pragma unroll
    for (int i = 0; i < 2; i++)
#pragma unroll
      for (int nt = 0; nt < 4; nt++)
        acc[i][nt] = mfma16(av[kt][i], bw[kt][nt], acc[i][nt]);

#pragma unroll
  for (int nt = 0; nt < 4; nt++){
    const int col = nblk*64 + nt*16 + l16;
    const float bias = pb[col];
#pragma unroll
    for (int i = 0; i < 2; i++)
#pragma unroll
      for (int r = 0; r < 4; r++){
        const int row = mblk*128 + (wave*2 + i)*16 + quad*4 + r;
        out[(size_t)row*192 + col] = acc[i][nt][r] + bias;
      }
  }
}

extern "C" void kernel_launch(void* const* d_in, const int* in_sizes, int n_in,
                              void* d_out, int out_size, void* d_ws, size_t ws_size,
                              hipStream_t stream) {
  (void)in_sizes; (void)n_in; (void)out_size; (void)ws_size;
  const float* x      = (const float*)d_in[0];
  const float* gamma  = (const float*)d_in[1];
  const float* rpb    = (const float*)d_in[2];
  const float* qkv_w  = (const float*)d_in[3];
  const float* qkv_b  = (const float*)d_in[4];
  const float* proj_w = (const float*)d_in[5];
  const float* proj_b = (const float*)d_in[6];

  unsigned short* wq   = (unsigned short*)d_ws;            // 576*192 bf16
  unsigned short* wp   = wq + 576*192;                     // 192*192 bf16
  float* bt            = (float*)(wp + 192*192);           // 6*64*64 fp32 (transposed)
  unsigned short* attn = (unsigned short*)(bt + 6*64*64);  // 100352*192 bf16

  // xng (2048*64*192 bf16 = 50.3 MB) lives in d_out scratch (77 MB fp32 output buffer,
  // dead until wa_k2 writes it — wa_k2 reads only attn/wp).
  unsigned short* xng = (unsigned short*)d_out;
  float* out = (float*)d_out;

  hipLaunchKernelGGL(wa_ln, dim3(32768), dim3(256), 0, stream,
                     x, gamma, xng, qkv_w, proj_w, rpb, wq, wp, bt);
  hipLaunchKernelGGL(wa_k1, dim3(4096), dim3(384), 0, stream,
                     xng, bt, wq, qkv_b, attn);
  hipLaunchKernelGGL(wa_k2, dim3(784, 3), dim3(256), 0, stream,
                     attn, wp, proj_b, out);
}

// Round 3
// 305.984 us; speedup vs baseline: 1.5734x; 1.5734x over previous
//
#include <hip/hip_runtime.h>

// WindowAttention MFMA v5: B=32, 56x56, C=192, heads=6, d=32, ws=7, NW=49
//  ln:   prep folded + LayerNorm -> xng in d_out scratch, rows 49..63 zeroed.
//        v5: xng written XOR-SWIZZLED per row (short idx ^= (row&7)<<3) so k1 can
//        stage it linearly via global_load_lds and still read bank-conflict-free.
//  k1:   per (window, 3-head half). v5 changes:
//        - xn tile (24KB) staged async into LDS via global_load_lds (0 VGPR cost,
//          1 round-trip instead of 6 serial ones for A-frags)
//        - Q|K interleaved stride-72 rows (27.6KB); vt overlays xn after barrier
//          -> LDS 52.2KB -> 3 blocks/CU kept
//        - XCD-aware blockIdx swizzle (window half-pairs share an XCD L2)
//  k2:   proj GEMM. v5: preload A-frags only (48 VGPR, safe), B per-kt (L2-hot).

typedef __bf16 bf16x8 __attribute__((ext_vector_type(8)));
typedef float  f32x4  __attribute__((ext_vector_type(4)));
typedef unsigned int u32;
union U128 { uint4 u; bf16x8 v; };

__device__ __forceinline__ f32x4 mfma16(bf16x8 a, bf16x8 b, f32x4 c){
  return __builtin_amdgcn_mfma_f32_16x16x32_bf16(a, b, c, 0, 0, 0);
}
__device__ __forceinline__ f32x4 f4zero(){
  f32x4 z; z[0]=0.f; z[1]=0.f; z[2]=0.f; z[3]=0.f; return z;
}
__device__ __forceinline__ unsigned short f2bf(float f){
  union{float f; unsigned int i;} x; x.f = f;
  unsigned int r = x.i + 0x7fffu + ((x.i >> 16) & 1u);  // RNE
  return (unsigned short)(r >> 16);
}
__device__ __forceinline__ bf16x8 ldfrag(const unsigned short* p){
  U128 x; x.u = *(const uint4*)p; return x.v;
}
__device__ __forceinline__ int div7(int t){ return (t * 9363) >> 16; }  // exact for t<64

// async 16B/lane global -> LDS (wave-uniform LDS base + lane*16)
__device__ __forceinline__ void glds16(const unsigned short* g, unsigned short* l){
  __builtin_amdgcn_global_load_lds((const __attribute__((address_space(1))) u32*)g,
                                   (__attribute__((address_space(3))) u32*)l, 16, 0, 0);
}

// ---------------- ln: prep (folded) + LayerNorm + window partition -> xng ----------------
// grid 32768 x 256 (4 waves/block, 1 row/wave). xng[wi*64 + t][192] SWIZZLED per row.
__global__ __launch_bounds__(256, 8) void wa_ln(
    const float* __restrict__ x, const float* __restrict__ gamma,
    unsigned short* __restrict__ xng,
    const float* __restrict__ qkv_w, const float* __restrict__ proj_w,
    const float* __restrict__ rpb,
    unsigned short* __restrict__ wq, unsigned short* __restrict__ wp,
    float* __restrict__ bt)
{
  const int tid  = threadIdx.x;

  // --- folded prep (first 432 blocks) ---
  if (blockIdx.x < 432){
    int i = blockIdx.x * 256 + tid;
    if (i < 576*192) wq[i] = f2bf(qkv_w[i]);
    if (i < 192*192) wp[i] = f2bf(proj_w[i]);
    if (i < 6*64*64){
      // btT layout: [head][t][l16][nt] so one lane reads its 4 bias values as a dwordx4
      int head = i >> 12, t = (i >> 6) & 63, j = i & 63;
      int l16 = j >> 2, nt = j & 3;
      int col = nt*16 + l16;
      float v;
      if (t < 49 && col < 49){
        int tr = div7(t),   tc = t   - tr*7;
        int jr = div7(col), jc = col - jr*7;
        v = rpb[((tr - jr + 6)*13 + (tc - jc + 6))*6 + head];
      } else {
        v = (col >= 49) ? -3.0e38f : 0.0f;  // mask folded into bias
      }
      bt[i] = v;
    }
  }

  // --- LayerNorm ---
  const int wave = tid >> 6, lane = tid & 63;
  const int wid  = blockIdx.x * 4 + wave;        // wi*64 + t
  const int wi   = wid >> 6, t = wid & 63;
  unsigned short* dst = xng + (size_t)wid * 192;
  if (t >= 49){
    // zeros: swizzle is a within-row permutation of a constant row -> plain write ok
    if (lane < 24){ const uint4 z = {0u,0u,0u,0u}; *(uint4*)&dst[lane*8] = z; }
    return;
  }
  const int b = wi >> 6, wr = (wi >> 3) & 7, wc = wi & 7;
  const int tr = div7(t), tc = t - tr*7;
  const float* xt = x + ((size_t)b*3136 + (size_t)((wr*7 + tr)*56 + wc*7 + tc)) * 192;
  float v0 = xt[lane], v1 = xt[lane+64], v2 = xt[lane+128];
  float s  = v0 + v1 + v2;
  float sq = v0*v0 + v1*v1 + v2*v2;
#pragma unroll
  for (int off = 32; off > 0; off >>= 1){
    s  += __shfl_xor(s,  off);
    sq += __shfl_xor(sq, off);
  }
  float mu  = s * (1.0f/192.0f);
  float var = sq * (1.0f/192.0f) - mu*mu;
  float inv = rsqrtf(var + 1e-5f);
  const int sw = (t & 7) << 3;                   // XOR on short-index bits 3..5 (byte bits 4..6)
  dst[lane        ^ sw] = f2bf((v0 - mu)*inv*gamma[lane]);
  dst[(lane + 64) ^ sw] = f2bf((v1 - mu)*inv*gamma[lane+64]);
  dst[(lane + 128)^ sw] = f2bf((v2 - mu)*inv*gamma[lane+128]);
}

// ---------------- k1: QKV + attention (MFMA), LDS = 52.2 KB -> 3 blocks/CU ----------------
// grid 4096 = 2048 windows x 2 half (3 heads each); block 384 (6 waves)
__global__ __launch_bounds__(384, 5) void wa_k1(
    const unsigned short* __restrict__ xng, const float* __restrict__ bt,
    const unsigned short* __restrict__ wq, const float* __restrict__ qkv_b,
    unsigned short* __restrict__ attn)
{
  // qk: [hl][row][{q 0..31, k 32..63, pad 64..71}] stride 72; P overlays after QK^T barrier
  __shared__ __align__(16) unsigned short qk[3*64*72];     // 27648 B
  // xn: staged window tile [64][192] (swizzled content); vt overlays after post-MFMA barrier
  __shared__ __align__(16) unsigned short xnb[64*192];     // 24576 B

  // XCD swizzle: physical id p -> logical blk so blk pairs (window halves) and
  // neighboring windows land on the same XCD L2. 4096 % 8 == 0 -> bijective.
  const int p    = blockIdx.x;
  const int blk  = (p & 7) * 512 + (p >> 3);
  const int wi   = blk >> 1;
  const int h0   = (blk & 1) * 3;
  const int b    = wi >> 6;
  const int wr   = (wi >> 3) & 7;
  const int wc   = wi & 7;
  const int tid  = threadIdx.x;
  const int wave = tid >> 6;
  const int lane = tid & 63;
  const int quad = lane >> 4;
  const int l16  = lane & 15;

  // ---- async stage xn tile (24 KB): 6 waves x 4 chunks x (64 lanes x 16B) ----
  {
    const unsigned short* xw = xng + (size_t)wi * 64 * 192;
#pragma unroll
    for (int j = 0; j < 4; j++){
      const int chunk = wave*4 + j;               // 0..23, wave-uniform
      glds16(xw + chunk*512 + lane*8, &xnb[chunk*512]);
    }
  }
  __syncthreads();   // drains vmcnt -> xn staged

  // ---- QKV GEMM: wave w: section sec=w>>1 (q/k/v), 48 cols; A from LDS, B per-kt ----
  f32x4 acc[4][3];
  {
    const int sec = wave >> 1;
    const int n0  = sec*192 + h0*32 + (wave & 1)*48;
#pragma unroll
    for (int mt = 0; mt < 4; mt++)
#pragma unroll
      for (int nt = 0; nt < 3; nt++) acc[mt][nt] = f4zero();

#pragma unroll
    for (int kt = 0; kt < 6; kt++){
      bf16x8 a[4], bw[3];
#pragma unroll
      for (int nt = 0; nt < 3; nt++)
        bw[nt] = ldfrag(&wq[(size_t)(n0 + nt*16 + l16)*192 + kt*32 + quad*8]);
#pragma unroll
      for (int mt = 0; mt < 4; mt++)
        a[mt] = ldfrag(&xnb[(mt*16 + l16)*192 + ((kt*32 + quad*8) ^ ((l16 & 7) << 3))]);
#pragma unroll
      for (int mt = 0; mt < 4; mt++)
#pragma unroll
        for (int nt = 0; nt < 3; nt++)
          acc[mt][nt] = mfma16(a[mt], bw[nt], acc[mt][nt]);
    }
  }
  __syncthreads();   // all waves done reading xn -> safe to overlay vt on xnb

  // ---- epilogue: write Q|K (qk, stride 72) and V^T (vt = xnb overlay, stride 72) ----
  unsigned short* const vt = xnb;                 // [hl][d 0..31][t 0..63] stride 72
  {
    const int sec = wave >> 1;
    const int n0  = sec*192 + h0*32 + (wave & 1)*48;
    const float scale = 0.17677669529663687f;     // 1/sqrt(32)
#pragma unroll
    for (int nt = 0; nt < 3; nt++){
      const int bc = (wave & 1)*48 + nt*16 + l16; // 0..95 within section
      const int hl2 = bc >> 5, d = bc & 31;
      const float bias = qkv_b[n0 + nt*16 + l16];
#pragma unroll
      for (int mt = 0; mt < 4; mt++)
#pragma unroll
        for (int r = 0; r < 4; r++){
          const int row = mt*16 + quad*4 + r;
          const float val = acc[mt][nt][r] + bias;
          if (sec == 0)      qk[(hl2*64 + row)*72 + d]      = f2bf(val * scale);
          else if (sec == 1) qk[(hl2*64 + row)*72 + 32 + d] = f2bf(val);
          else               vt[(hl2*32 + d)*72 + row]      = f2bf(val);
        }
    }
  }
  __syncthreads();

  // ---- Attention: wave -> (local head hl = w>>1, row-half = w&1) ----
  const int hl   = wave >> 1;
  const int half = wave & 1;
  const int head = h0 + hl;

  // bias prefetch (one dwordx4 per row) — issue first, hides under QK ds_reads/MFMAs
  f32x4 bias4[2][4];
#pragma unroll
  for (int i = 0; i < 2; i++)
#pragma unroll
    for (int r = 0; r < 4; r++){
      const int t = half*32 + i*16 + quad*4 + r;
      bias4[i][r] = *(const f32x4*)&bt[head*4096 + t*64 + l16*4];
    }

  // QK^T (consumes qk)
  bf16x8 aq[2];
#pragma unroll
  for (int i = 0; i < 2; i++)
    aq[i] = ldfrag(&qk[(hl*64 + half*32 + i*16 + l16)*72 + quad*8]);

  f32x4 s[2][4];
#pragma unroll
  for (int nt = 0; nt < 4; nt++){
    bf16x8 bk = ldfrag(&qk[(hl*64 + nt*16 + l16)*72 + 32 + quad*8]);
#pragma unroll
    for (int i = 0; i < 2; i++)
      s[i][nt] = mfma16(aq[i], bk, f4zero());
  }

  __syncthreads();   // Q/K now dead everywhere -> safe to overlay P

  // ---- softmax rows; write P (stride 72) over qk region; keep 1/l ----
  float linv[2][4];
#pragma unroll
  for (int i = 0; i < 2; i++)
#pragma unroll
    for (int r = 0; r < 4; r++){
      const f32x4 b4 = bias4[i][r];
#pragma unroll
      for (int nt = 0; nt < 4; nt++) s[i][nt][r] += b4[nt];
      float m = fmaxf(fmaxf(s[i][0][r], s[i][1][r]), fmaxf(s[i][2][r], s[i][3][r]));
#pragma unroll
      for (int off = 8; off > 0; off >>= 1) m = fmaxf(m, __shfl_xor(m, off));
      float l = 0.f;
      const int t = half*32 + i*16 + quad*4 + r;
#pragma unroll
      for (int nt = 0; nt < 4; nt++){
        float pexp = __expf(s[i][nt][r] - m);
        l += pexp;
        qk[hl*4608 + t*72 + nt*16 + l16] = f2bf(pexp);
      }
#pragma unroll
      for (int off = 8; off > 0; off >>= 1) l += __shfl_xor(l, off);
      linv[i][r] = 1.f / l;
    }

  // ---- PV: O(32x32 slice) = P rows[half*32..+32) x V(64x32) ----
  f32x4 o[2][2];
#pragma unroll
  for (int i = 0; i < 2; i++)
#pragma unroll
    for (int n2 = 0; n2 < 2; n2++) o[i][n2] = f4zero();
#pragma unroll
  for (int kt = 0; kt < 2; kt++){
    bf16x8 ap[2], bv[2];
#pragma unroll
    for (int i = 0; i < 2; i++)
      ap[i] = ldfrag(&qk[hl*4608 + (half*32 + i*16 + l16)*72 + kt*32 + quad*8]);
#pragma unroll
    for (int n2 = 0; n2 < 2; n2++)
      bv[n2] = ldfrag(&vt[(hl*32 + n2*16 + l16)*72 + kt*32 + quad*8]);
#pragma unroll
    for (int i = 0; i < 2; i++)
#pragma unroll
      for (int n2 = 0; n2 < 2; n2++)
        o[i][n2] = mfma16(ap[i], bv[n2], o[i][n2]);
  }

  // store O rows < 49, spatial order (window reverse), bf16
#pragma unroll
  for (int i = 0; i < 2; i++)
#pragma unroll
    for (int r = 0; r < 4; r++){
      const int t = half*32 + i*16 + quad*4 + r;
      if (t < 49){
        const int tr = div7(t), tcc = t - tr*7;
        const size_t base =
          ((size_t)b*3136 + (size_t)((wr*7 + tr)*56 + wc*7 + tcc))*192 + head*32;
        const float inv = linv[i][r];
        attn[base + l16]      = f2bf(o[i][0][r] * inv);
        attn[base + 16 + l16] = f2bf(o[i][1][r] * inv);
      }
    }
}

// ---------------- k2: proj GEMM direct-global (no LDS, no barrier) ----------------
// grid (784, 3); block 256 (4 waves); per block M=128, N=64; K=192.
// v5: preload all 12 A-frags (48 VGPR, one exposed round-trip); B per-kt (L2-hot).
__global__ __launch_bounds__(256, 4) void wa_k2(
    const unsigned short* __restrict__ a, const unsigned short* __restrict__ wp,
    const float* __restrict__ pb, float* __restrict__ out)
{
  const int mblk = blockIdx.x;
  const int nblk = blockIdx.y;
  const int tid  = threadIdx.x;
  const int wave = tid >> 6;
  const int lane = tid & 63;
  const int quad = lane >> 4;
  const int l16  = lane & 15;

  bf16x8 av[6][2];
#pragma unroll
  for (int kt = 0; kt < 6; kt++)
#pragma unroll
    for (int i = 0; i < 2; i++)
      av[kt][i] = ldfrag(&a[(size_t)(mblk*128 + (wave*2 + i)*16 + l16)*192 + kt*32 + quad*8]);
  __builtin_amdgcn_sched_barrier(0);   // keep the 12 A loads issued up front

  f32x4 acc[2][4];
#pragma unroll
  for (int i = 0; i < 2; i++)
#pragma unroll
    for (int nt = 0; nt < 4; nt++) acc[i][nt] = f4zero();

#pragma unroll
  for (int kt = 0; kt < 6; kt++){
    bf16x8 bw[4];
#pragma unroll
    for (int nt = 0; nt < 4; nt++)
      bw[nt] = ldfrag(&wp[(size_t)(nblk*64 + nt*16 + l16)*192 + kt*32 + quad*8]);
#pragma unroll
    for (int i = 0; i < 2; i++)
#pragma unroll
      for (int nt = 0; nt < 4; nt++)
        acc[i][nt] = mfma16(av[kt][i], bw[nt], acc[i][nt]);
  }

#pragma unroll
  for (int nt = 0; nt < 4; nt++){
    const int col = nblk*64 + nt*16 + l16;
    const float bias = pb[col];
#pragma unroll
    for (int i = 0; i < 2; i++)
#pragma unroll
      for (int r = 0; r < 4; r++){
        const int row = mblk*128 + (wave*2 + i)*16 + quad*4 + r;
        out[(size_t)row*192 + col] = acc[i][nt][r] + bias;
      }
  }
}

extern "C" void kernel_launch(void* const* d_in, const int* in_sizes, int n_in,
                              void* d_out, int out_size, void* d_ws, size_t ws_size,
                              hipStream_t stream) {
  (void)in_sizes; (void)n_in; (void)out_size; (void)ws_size;
  const float* x      = (const float*)d_in[0];
  const float* gamma  = (const float*)d_in[1];
  const float* rpb    = (const float*)d_in[2];
  const float* qkv_w  = (const float*)d_in[3];
  const float* qkv_b  = (const float*)d_in[4];
  const float* proj_w = (const float*)d_in[5];
  const float* proj_b = (const float*)d_in[6];

  unsigned short* wq   = (unsigned short*)d_ws;            // 576*192 bf16
  unsigned short* wp   = wq + 576*192;                     // 192*192 bf16
  float* bt            = (float*)(wp + 192*192);           // 6*64*64 fp32 (transposed)
  unsigned short* attn = (unsigned short*)(bt + 6*64*64);  // 100352*192 bf16

  // xng (2048*64*192 bf16 = 50.3 MB, row-swizzled) lives in d_out scratch (77 MB fp32
  // output buffer, dead until wa_k2 writes it — wa_k2 reads only attn/wp).
  unsigned short* xng = (unsigned short*)d_out;
  float* out = (float*)d_out;

  hipLaunchKernelGGL(wa_ln, dim3(32768), dim3(256), 0, stream,
                     x, gamma, xng, qkv_w, proj_w, rpb, wq, wp, bt);
  hipLaunchKernelGGL(wa_k1, dim3(4096), dim3(384), 0, stream,
                     xng, bt, wq, qkv_b, attn);
  hipLaunchKernelGGL(wa_k2, dim3(784, 3), dim3(256), 0, stream,
                     attn, wp, proj_b, out);
}